// Round 1
// baseline (1726.977 us; speedup 1.0000x reference)
//
#include <hip/hip_runtime.h>
#include <hip/hip_cooperative_groups.h>

namespace cg = cooperative_groups;

// N=512 state dim, L=16384 steps, chunk T=1024, P=16 chunks.
#define NDIM 512
#define LSEQ 16384
#define TCH  1024
#define PCH  16

#define DTF  (1.0f/16384.0f)
#define DT2F (0.5f/16384.0f)

// ---------------------------------------------------------------------------
// gkt: one 32x32-output GEMM task per 256-thread block, 4-wave K-split with
// private LDS staging, cross-wave LDS reduce. K must be a multiple of 64.
// D[row0+32, col0+32] = alpha * A[row0.., 0..K) @ B[0..K, col0..).
// smem: 4 regions x 1152 floats. Entry __syncthreads guards smem reuse when
// one block runs several tasks back-to-back.
// ---------------------------------------------------------------------------
__device__ __forceinline__ void gkt(float* smem,
    const float* A, int lda, const float* B, int ldb,
    float* D, int ldd, int row0, int col0, int K, float alpha)
{
    __syncthreads();
    const int tid  = threadIdx.x;
    const int w    = tid >> 6;
    const int lane = tid & 63;
    const int ty = lane >> 3, tx = lane & 7;          // 8x8 lane grid, 4x4 micro

    float* As = smem + w * 1152;          // As[k][r] = As[k*36 + r]
    float* Bs = As + 576;                 // Bs[k][c] = Bs[k*36 + c]

    const int Kc    = K >> 2;             // per-wave K chunk (mult of 16)
    const int steps = Kc >> 4;
    const int kbase = w * Kc;

    float acc[4][4] = {};

    for (int s = 0; s < steps; ++s) {
        const int kb = kbase + s * 16;
#pragma unroll
        for (int i = 0; i < 2; ++i) {     // stage A (transpose), 2 float4/lane
            int idx = lane + 64 * i;
            int r = idx >> 2, cg2 = (idx & 3) * 4;
            float4 v = *(const float4*)(A + (size_t)(row0 + r) * lda + kb + cg2);
            As[(cg2 + 0) * 36 + r] = v.x; As[(cg2 + 1) * 36 + r] = v.y;
            As[(cg2 + 2) * 36 + r] = v.z; As[(cg2 + 3) * 36 + r] = v.w;
        }
#pragma unroll
        for (int i = 0; i < 2; ++i) {     // stage B, 2 float4/lane
            int idx = lane + 64 * i;
            int kr = idx >> 3, cg2 = (idx & 7) * 4;
            *(float4*)(Bs + kr * 36 + cg2) =
                *(const float4*)(B + (size_t)(kb + kr) * ldb + col0 + cg2);
        }
        __syncthreads();
#pragma unroll
        for (int kk = 0; kk < 16; ++kk) {
            float4 a = *(const float4*)(As + kk * 36 + 4 * ty);
            float4 b = *(const float4*)(Bs + kk * 36 + 4 * tx);
            acc[0][0] += a.x * b.x; acc[0][1] += a.x * b.y; acc[0][2] += a.x * b.z; acc[0][3] += a.x * b.w;
            acc[1][0] += a.y * b.x; acc[1][1] += a.y * b.y; acc[1][2] += a.y * b.z; acc[1][3] += a.y * b.w;
            acc[2][0] += a.z * b.x; acc[2][1] += a.z * b.y; acc[2][2] += a.z * b.z; acc[2][3] += a.z * b.w;
            acc[3][0] += a.w * b.x; acc[3][1] += a.w * b.y; acc[3][2] += a.w * b.z; acc[3][3] += a.w * b.w;
        }
        __syncthreads();
    }

    // per-wave partial (32x32) into own region
    float* red = smem + w * 1152;
#pragma unroll
    for (int i = 0; i < 4; ++i)
        *(float4*)(red + (4 * ty + i) * 32 + 4 * tx) =
            make_float4(acc[i][0], acc[i][1], acc[i][2], acc[i][3]);
    __syncthreads();

    float4 s0 = *(const float4*)(smem + 0 * 1152 + tid * 4);
    float4 s1 = *(const float4*)(smem + 1 * 1152 + tid * 4);
    float4 s2 = *(const float4*)(smem + 2 * 1152 + tid * 4);
    float4 s3 = *(const float4*)(smem + 3 * 1152 + tid * 4);
    float4 r4 = make_float4(alpha * (s0.x + s1.x + s2.x + s3.x),
                            alpha * (s0.y + s1.y + s2.y + s3.y),
                            alpha * (s0.z + s1.z + s2.z + s3.z),
                            alpha * (s0.w + s1.w + s2.w + s3.w));
    int r = tid >> 3, c = (tid & 7) * 4;
    // scalar stores: D base may be only 4B-aligned (V+m slab writes, m=1,2)
    float* dp = D + (size_t)(row0 + r) * ldd + col0 + c;
    dp[0] = r4.x; dp[1] = r4.y; dp[2] = r4.z; dp[3] = r4.w;
}

// ---------------------------------------------------------------------------
// diag_inv_task: invert one diagonal 64x64 block of M = I - dt/2*A into W.
// Threads 0..63 active; full i-loop unroll keeps xcol[] in registers.
// ---------------------------------------------------------------------------
__device__ __forceinline__ void diag_inv_task(float* smem, const float* Ain,
                                              float* W, int blk)
{
    __syncthreads();
    float (*sh)[65] = (float (*)[65])smem;       // 64*65 = 4160 floats
    const int base = blk * 64;
    const int lane = threadIdx.x;
    if (lane < 64)
        for (int r = 0; r < 64; ++r)
            sh[r][lane] = ((r == lane) ? 1.f : 0.f)
                        - DT2F * Ain[(size_t)(base + r) * NDIM + base + lane];
    __syncthreads();
    if (lane < 64) {
        float xcol[64];
#pragma unroll
        for (int i = 0; i < 64; ++i) {
            float dot = 0.f;
#pragma unroll
            for (int k = 0; k < i; ++k) dot += sh[i][k] * xcol[k];
            xcol[i] = (((lane == i) ? 1.f : 0.f) - dot) / sh[i][i];
        }
#pragma unroll
        for (int k = 0; k < 64; ++k)
            W[(size_t)(base + k) * NDIM + base + lane] = xcol[k];
    }
}

// ---------------------------------------------------------------------------
// scan_phase: one Kogge-Stone round over 16 chunks, per-wave 512-dot with
// triangular K clipping (G is lower-triangular).
// ---------------------------------------------------------------------------
__device__ __forceinline__ void scan_phase(const float* G, const float* Zin,
    float* Zout, const float* hs, float* Hmat, float* hfin,
    int o, int last, int nb, int b0, int wv, int lane)
{
    for (int t = b0; t < 2048; t += nb) {
        int wid = t * 4 + wv;
        int p = wid & (PCH - 1), i = wid >> 4;
        float dot = 0.f;
        if (p >= o) {
            const float* gr = G + (size_t)i * NDIM;
            const float* zc = Zin + (size_t)(p - o) * NDIM;
            int rmax = i >> 6;
            for (int rr = 0; rr <= rmax; ++rr) {
                int k = (rr << 6) + lane;
                if (k <= i) dot += gr[k] * zc[k];
            }
#pragma unroll
            for (int off = 32; off; off >>= 1) dot += __shfl_xor(dot, off, 64);
        }
        if (lane == 0) {
            float z = Zin[(size_t)p * NDIM + i] + dot;
            Zout[(size_t)p * NDIM + i] = z;
            if (last) {
                if (p < PCH - 1) Hmat[(size_t)(p + 1) * NDIM + i] = z;
                else hfin[i] = z;
                if (p == 0) Hmat[i] = hs[i];
            }
        }
    }
}

// ---------------------------------------------------------------------------
// The whole pipeline as one cooperative kernel. 26 grid.sync()s replace 31
// dependent launches. All phases are grid-stride task loops (any grid size).
// ---------------------------------------------------------------------------
__global__ __launch_bounds__(256, 4) void ssm_mega(
    const float* x, const float* hs, const float* Ain,
    const float* Bv, const float* C, float* out, float* ws)
{
    cg::grid_group grid = cg::this_grid();
    __shared__ float smem[4608];

    const int MM = NDIM * NDIM;
    float* Ab    = ws;
    float* P0    = Ab + MM;
    float* P1    = P0 + MM;
    float* GA    = P1 + MM;                    // Ab^1024
    float* GB    = GA + MM;                    // Ab^2048
    float* GC    = GB + MM;                    // Ab^4096
    float* GD    = GC + MM;                    // Ab^8192
    float* V     = GD + MM;                    // 512 x 1024
    float* Crows = V + NDIM * TCH;             // 1024 x 512
    float* CrowsS= Crows + TCH * NDIM;         // 1024 x 512 (first 1MB = W)
    float* kv    = CrowsS + TCH * NDIM;        // 1024
    float* Bbc   = kv + TCH;                   // 512
    float* U     = Bbc + NDIM;                 // 16 x 512
    float* Z0    = U + PCH * NDIM;
    float* Z1    = Z0 + PCH * NDIM;
    float* Hmat  = Z1 + PCH * NDIM;
    float* W = CrowsS;   // W dead after phase 2; CrowsS written in epilogue
    float* T = P0;       // pair temp; P0 fully rewritten (lower) in round 0

    const int nb   = gridDim.x;
    const int b0   = blockIdx.x;
    const int tid  = threadIdx.x;
    const int wv   = tid >> 6;
    const int lane = tid & 63;

    // ===== phase 0: zero W off-diag + P0..GD (keeps uppers exactly 0 so the
    // triangular-K extension reads exact zeros); invert 8 diagonal blocks ====
    for (int t = b0; t < 456; t += nb) {
        if (t < 8) {
            diag_inv_task(smem, Ain, W, t);
        } else if (t < 72) {               // W: 65536 float4, skip diag blocks
            int base = (t - 8) * 1024;
#pragma unroll
            for (int u = 0; u < 4; ++u) {
                int f = base + u * 256 + tid;
                int i = f >> 7, c4 = f & 127;
                if ((i >> 6) != (c4 >> 4))
                    ((float4*)W)[f] = make_float4(0.f, 0.f, 0.f, 0.f);
            }
        } else {                           // P0..GD: 393216 float4
            int base = (t - 72) * 1024;
#pragma unroll
            for (int u = 0; u < 4; ++u)
                ((float4*)P0)[base + u * 256 + tid] = make_float4(0.f, 0.f, 0.f, 0.f);
        }
    }
    grid.sync();

    // ===== phase 1: blocked inversion pair levels s = 64,128,256 =====
    for (int s = 64; s <= 256; s <<= 1) {
        const int np = NDIM / (2 * s), ntx = s >> 5, tt = ntx * ntx;
        for (int t = b0; t < tt * np; t += nb) {      // T = A21 @ W11
            int pair = t / tt, tile = t - pair * tt;
            int it = tile / ntx, jt = tile - it * ntx;
            int o = pair * 2 * s;
            gkt(smem, Ain + (size_t)(o + s) * NDIM + o, NDIM,
                W + (size_t)o * NDIM + o, NDIM,
                T + (size_t)(o + s) * NDIM + o, NDIM,
                it * 32, jt * 32, s, 1.f);
        }
        grid.sync();
        for (int t = b0; t < tt * np; t += nb) {      // W21 = dt/2 * W22 @ T
            int pair = t / tt, tile = t - pair * tt;
            int it = tile / ntx, jt = tile - it * ntx;
            int o = pair * 2 * s;
            gkt(smem, W + (size_t)(o + s) * NDIM + (o + s), NDIM,
                T + (size_t)(o + s) * NDIM + o, NDIM,
                W + (size_t)(o + s) * NDIM + o, NDIM,
                it * 32, jt * 32, s, DT2F);
        }
        grid.sync();
    }

    // ===== phase 2: Ab = 2W - I ; Bb = dt*W@Bv ; Crows row0 = C =====
    for (int t = b0; t < 385; t += nb) {
        if (t < 256) {
            int idx = t * 256 + tid;
            int i = idx >> 7, j0 = (idx & 127) << 2;
            float4 wq = *(const float4*)(W + (size_t)i * NDIM + j0);
            float4 r = make_float4(2.f * wq.x, 2.f * wq.y, 2.f * wq.z, 2.f * wq.w);
            if (i == j0)          r.x -= 1.f;
            else if (i == j0 + 1) r.y -= 1.f;
            else if (i == j0 + 2) r.z -= 1.f;
            else if (i == j0 + 3) r.w -= 1.f;
            *(float4*)(Ab + (size_t)i * NDIM + j0) = r;
        } else if (t < 384) {
            int i = (t - 256) * 4 + wv;
            float s = 0.f;
#pragma unroll
            for (int c = 0; c < 8; ++c) {
                int k = (c << 6) + lane;
                s += W[(size_t)i * NDIM + k] * Bv[k];
            }
#pragma unroll
            for (int off = 32; off; off >>= 1) s += __shfl_xor(s, off, 64);
            if (lane == 0) {
                float bb = DTF * s;
                V[(size_t)i * TCH] = bb;
                Bbc[i] = bb;
            }
        } else {
            Crows[tid]       = C[tid];
            Crows[tid + 256] = C[tid + 256];
        }
    }
    grid.sync();

    // ===== phases 3..15: 13 doubling rounds =====
    // z2: gnew = g@g, lower tiles only (g lower-triangular, uppers stay 0).
    // z0: V[:, m:m+32*nmx) = g @ V[:, :..)    (triangular K clip on g rows)
    // z1: Crows[m:..,:] = Crows[..] @ g       (triangular K clip on g cols)
    // For m<32 the 32-wide slab writes garbage into cols/rows [2m, m+32),
    // which later rounds overwrite before any consumer reads them.
    const float* g = Ab;
    int m = 1;
    for (int r = 0; r < 13; ++r) {
        float* gn = (r == 12) ? GD : (r == 11) ? GC : (r == 10) ? GB :
                    (r == 9)  ? GA : ((r & 1) ? P1 : P0);
        const int nmx   = (m >= 32) ? (m >> 5) : 1;
        const int lognx = (m >= 32) ? (r - 5) : 0;
        const int nz    = (m >= TCH) ? 0 : 16 * nmx;
        const int ntot  = 136 + 2 * nz;
        for (int t = b0; t < ntot; t += nb) {
            if (t < 136) {                              // z2 lower tile
                int it = (int)((sqrtf(8.f * (float)t + 1.f) - 1.f) * 0.5f);
                while ((it + 1) * (it + 2) / 2 <= t) ++it;
                while (it * (it + 1) / 2 > t) --it;
                int jt = t - it * (it + 1) / 2;
                int k0 = (jt * 32) & ~63;
                int ke = (it * 32 + 32 + 63) & ~63; if (ke > NDIM) ke = NDIM;
                gkt(smem, g + k0, NDIM, g + (size_t)k0 * NDIM, NDIM,
                    gn, NDIM, it * 32, jt * 32, ke - k0, 1.f);
            } else if (t < 136 + nz) {                  // z0: V doubling
                int u = t - 136;
                int it = u >> lognx, jt = u & (nmx - 1);
                int ke = (it * 32 + 32 + 63) & ~63; if (ke > NDIM) ke = NDIM;
                gkt(smem, g, NDIM, V, TCH, V + m, TCH,
                    it * 32, jt * 32, ke, 1.f);
            } else {                                    // z1: Crows doubling
                int u = t - 136 - nz;
                int it = u >> 4, jt = u & 15;
                int col0 = jt * 32, k0 = col0 & ~63;
                gkt(smem, Crows + k0, NDIM, g + (size_t)k0 * NDIM, NDIM,
                    Crows + (size_t)m * NDIM, NDIM,
                    it * 32, col0, NDIM - k0, 1.f);
            }
        }
        grid.sync();
        g = gn; m <<= 1;
    }

    // ===== phase 16: CrowsS = Crows@Ab (tri-K) ; kv ; build_u =====
    for (int t = b0; t < 2816; t += nb) {
        if (t < 512) {
            int it = t >> 4, jt = t & 15;
            int col0 = jt * 32, k0 = col0 & ~63;
            gkt(smem, Crows + k0, NDIM, Ab + (size_t)k0 * NDIM, NDIM,
                CrowsS, NDIM, it * 32, col0, NDIM - k0, 1.f);
        } else if (t < 768) {                           // kv[j] = Crows[j].Bb
            int j = (t - 512) * 4 + wv;
            const float* cr = Crows + (size_t)j * NDIM;
            float dot = 0.f;
#pragma unroll
            for (int rr = 0; rr < 2; ++rr) {
                int o = rr * 256 + lane * 4;
                float4 c4 = *(const float4*)(cr + o);
                float4 b4 = *(const float4*)(Bbc + o);
                dot += c4.x * b4.x + c4.y * b4.y + c4.z * b4.z + c4.w * b4.w;
            }
#pragma unroll
            for (int off = 32; off; off >>= 1) dot += __shfl_xor(dot, off, 64);
            if (lane == 0) kv[j] = dot;
        } else {                                        // build_u
            int wid = (t - 768) * 4 + wv;
            int p = wid & (PCH - 1), i = wid >> 4;
            const float* vr = V + (size_t)i * TCH;
            const float* xc = x + p * TCH;
            float s = 0.f;
#pragma unroll
            for (int rr = 0; rr < 16; ++rr) {
                int t2 = (rr << 6) + lane;
                s += vr[TCH - 1 - t2] * xc[t2];
            }
            if (p == 0) {                               // + GA@h0 (tri)
                const float* gr = GA + (size_t)i * NDIM;
                int rmax = i >> 6;
                for (int rr = 0; rr <= rmax; ++rr) {
                    int k = (rr << 6) + lane;
                    if (k <= i) s += gr[k] * hs[k];
                }
            }
#pragma unroll
            for (int off = 32; off; off >>= 1) s += __shfl_xor(s, off, 64);
            if (lane == 0) U[(size_t)p * NDIM + i] = s;
        }
    }
    grid.sync();

    // ===== phases 17..20: Kogge-Stone scan, offsets 1,2,4,8 =====
    scan_phase(GA, U,  Z0, hs, Hmat, out + LSEQ, 1, 0, nb, b0, wv, lane); grid.sync();
    scan_phase(GB, Z0, Z1, hs, Hmat, out + LSEQ, 2, 0, nb, b0, wv, lane); grid.sync();
    scan_phase(GC, Z1, Z0, hs, Hmat, out + LSEQ, 4, 0, nb, b0, wv, lane); grid.sync();
    scan_phase(GD, Z0, Z1, hs, Hmat, out + LSEQ, 8, 1, nb, b0, wv, lane); grid.sync();

    // ===== phase 21: fused emit =====
    for (int t = b0; t < 4096; t += nb) {
        int wid = t * 4 + wv;
        int p = wid & (PCH - 1), s2 = wid >> 4;
        const float* cr = CrowsS + (size_t)s2 * NDIM;
        const float* hp = Hmat + (size_t)p * NDIM;
        float dot = 0.f;
#pragma unroll
        for (int rr = 0; rr < 2; ++rr) {
            int o = rr * 256 + lane * 4;
            float4 c4 = *(const float4*)(cr + o);
            float4 h4 = *(const float4*)(hp + o);
            dot += c4.x * h4.x + c4.y * h4.y + c4.z * h4.z + c4.w * h4.w;
        }
        const float* xc = x + p * TCH;
        int rmax = s2 >> 6;
        for (int rr = 0; rr <= rmax; ++rr) {
            int t2 = (rr << 6) + lane;
            if (t2 <= s2) dot += kv[s2 - t2] * xc[t2];
        }
#pragma unroll
        for (int off = 32; off; off >>= 1) dot += __shfl_xor(dot, off, 64);
        if (lane == 0) out[p * TCH + s2] = dot;
    }
}

// ---------------------------------------------------------------------------
extern "C" void kernel_launch(void* const* d_in, const int* in_sizes, int n_in,
                              void* d_out, int out_size, void* d_ws, size_t ws_size,
                              hipStream_t stream)
{
    (void)in_sizes; (void)n_in; (void)out_size; (void)ws_size;
    const float* x  = (const float*)d_in[0];
    const float* hs = (const float*)d_in[1];
    const float* A  = (const float*)d_in[2];
    const float* Bv = (const float*)d_in[3];
    const float* C  = (const float*)d_in[4];
    float* out = (float*)d_out;                 // [y (16384) | h_final (512)]
    float* ws  = (float*)d_ws;

    // grid = co-resident capacity (cooperative launch requirement).
    // __launch_bounds__(256,4) guarantees >=4 blocks/CU (LDS 18.4KB also fits).
    static int nblk = 0;
    if (nblk == 0) {
        int dev = 0;
        hipGetDevice(&dev);
        hipDeviceProp_t prop;
        int ncu = 256;
        if (hipGetDeviceProperties(&prop, dev) == hipSuccess)
            ncu = prop.multiProcessorCount;
        int bpc = 0;
        if (hipOccupancyMaxActiveBlocksPerMultiprocessor(
                &bpc, (const void*)ssm_mega, 256, 0) != hipSuccess || bpc < 1)
            bpc = 4;
        long cap = (long)bpc * (long)ncu;
        nblk = (int)(cap < 2048 ? cap : 2048);
        if (nblk < 8) nblk = 8;
    }

    void* args[7];
    args[0] = (void*)&x;  args[1] = (void*)&hs; args[2] = (void*)&A;
    args[3] = (void*)&Bv; args[4] = (void*)&C;  args[5] = (void*)&out;
    args[6] = (void*)&ws;
    hipLaunchCooperativeKernel((const void*)ssm_mega, dim3(nblk), dim3(256),
                               args, 0, stream);
}

// Round 2
// 305.657 us; speedup vs baseline: 5.6500x; 5.6500x over previous
//
#include <hip/hip_runtime.h>

// N=512 state dim, L=16384 steps, chunk T=1024, P=16 chunks.
#define NDIM 512
#define LSEQ 16384
#define TCH  1024
#define PCH  16

#define DTF  (1.0f/16384.0f)
#define DT2F (0.5f/16384.0f)

// ---------------------------------------------------------------------------
// gkt: 32x32-output GEMM task, 4-wave K-split with private LDS staging and
// cross-wave LDS reduce. K must be a multiple of 64.
// D[row0..+32, col0..+32] = alpha * A[row0.., 0..K) @ B[0..K, col0..)
// smem: 4 regions x 1152 floats (18432 B).
// ---------------------------------------------------------------------------
__device__ __forceinline__ void gkt(float* smem,
    const float* A, int lda, const float* B, int ldb,
    float* D, int ldd, int row0, int col0, int K, float alpha)
{
    const int tid  = threadIdx.x;
    const int w    = tid >> 6;
    const int lane = tid & 63;
    const int ty = lane >> 3, tx = lane & 7;          // 8x8 lane grid, 4x4 micro

    float* As = smem + w * 1152;          // As[k][r] = As[k*36 + r]
    float* Bs = As + 576;                 // Bs[k][c] = Bs[k*36 + c]

    const int Kc    = K >> 2;             // per-wave K chunk (mult of 16)
    const int steps = Kc >> 4;
    const int kbase = w * Kc;

    float acc[4][4] = {};

    for (int s = 0; s < steps; ++s) {
        const int kb = kbase + s * 16;
#pragma unroll
        for (int i = 0; i < 2; ++i) {     // stage A (transpose), 2 float4/lane
            int idx = lane + 64 * i;
            int r = idx >> 2, cg2 = (idx & 3) * 4;
            float4 v = *(const float4*)(A + (size_t)(row0 + r) * lda + kb + cg2);
            As[(cg2 + 0) * 36 + r] = v.x; As[(cg2 + 1) * 36 + r] = v.y;
            As[(cg2 + 2) * 36 + r] = v.z; As[(cg2 + 3) * 36 + r] = v.w;
        }
#pragma unroll
        for (int i = 0; i < 2; ++i) {     // stage B, 2 float4/lane
            int idx = lane + 64 * i;
            int kr = idx >> 3, cg2 = (idx & 7) * 4;
            *(float4*)(Bs + kr * 36 + cg2) =
                *(const float4*)(B + (size_t)(kb + kr) * ldb + col0 + cg2);
        }
        __syncthreads();
#pragma unroll
        for (int kk = 0; kk < 16; ++kk) {
            float4 a = *(const float4*)(As + kk * 36 + 4 * ty);
            float4 b = *(const float4*)(Bs + kk * 36 + 4 * tx);
            acc[0][0] += a.x * b.x; acc[0][1] += a.x * b.y; acc[0][2] += a.x * b.z; acc[0][3] += a.x * b.w;
            acc[1][0] += a.y * b.x; acc[1][1] += a.y * b.y; acc[1][2] += a.y * b.z; acc[1][3] += a.y * b.w;
            acc[2][0] += a.z * b.x; acc[2][1] += a.z * b.y; acc[2][2] += a.z * b.z; acc[2][3] += a.z * b.w;
            acc[3][0] += a.w * b.x; acc[3][1] += a.w * b.y; acc[3][2] += a.w * b.z; acc[3][3] += a.w * b.w;
        }
        __syncthreads();
    }

    // per-wave partial (32x32) into own region, then cross-wave reduce
    float* red = smem + w * 1152;
#pragma unroll
    for (int i = 0; i < 4; ++i)
        *(float4*)(red + (4 * ty + i) * 32 + 4 * tx) =
            make_float4(acc[i][0], acc[i][1], acc[i][2], acc[i][3]);
    __syncthreads();

    float4 s0 = *(const float4*)(smem + 0 * 1152 + tid * 4);
    float4 s1 = *(const float4*)(smem + 1 * 1152 + tid * 4);
    float4 s2 = *(const float4*)(smem + 2 * 1152 + tid * 4);
    float4 s3 = *(const float4*)(smem + 3 * 1152 + tid * 4);
    float4 r4 = make_float4(alpha * (s0.x + s1.x + s2.x + s3.x),
                            alpha * (s0.y + s1.y + s2.y + s3.y),
                            alpha * (s0.z + s1.z + s2.z + s3.z),
                            alpha * (s0.w + s1.w + s2.w + s3.w));
    int r = tid >> 3, c = (tid & 7) * 4;
    // scalar stores: D base may be only 4B-aligned (V+m slab writes, m=1,2)
    float* dp = D + (size_t)(row0 + r) * ldd + col0 + c;
    dp[0] = r4.x; dp[1] = r4.y; dp[2] = r4.z; dp[3] = r4.w;
}

// triangular tile decode: t -> (it, jt) with jt <= it
__device__ __forceinline__ void tri_decode(int t, int& it, int& jt)
{
    it = (int)((sqrtf(8.f * (float)t + 1.f) - 1.f) * 0.5f);
    while ((it + 1) * (it + 2) / 2 <= t) ++it;
    while (it * (it + 1) / 2 > t) --it;
    jt = t - it * (it + 1) / 2;
}

// ---------------------------------------------------------------------------
// diag_inv: invert the 8 diagonal 64x64 blocks of M = I - dt/2*A into W.
// ---------------------------------------------------------------------------
__global__ __launch_bounds__(64) void diag_inv(const float* __restrict__ A,
                                               float* __restrict__ W)
{
    __shared__ float sh[64][65];
    const int base = blockIdx.x * 64;
    const int lane = threadIdx.x;

    for (int r = 0; r < 64; ++r)
        sh[r][lane] = ((r == lane) ? 1.f : 0.f)
                    - DT2F * A[(size_t)(base + r) * NDIM + base + lane];
    __syncthreads();

    float xcol[64];
#pragma unroll
    for (int i = 0; i < 64; ++i) {
        float dot = 0.f;
#pragma unroll
        for (int k = 0; k < i; ++k) dot += sh[i][k] * xcol[k];
        xcol[i] = (((lane == i) ? 1.f : 0.f) - dot) / sh[i][i];
    }
#pragma unroll
    for (int k = 0; k < 64; ++k)
        W[(size_t)(base + k) * NDIM + base + lane] = xcol[k];
}

// ---------------------------------------------------------------------------
// pair combines (blocked inversion). W11 lower-tri => clip K start on pairA2;
// W22 lower-tri => clip K end on pairB2.
// ---------------------------------------------------------------------------
__global__ __launch_bounds__(256) void pairA2(const float* __restrict__ A,
    const float* __restrict__ W, float* __restrict__ T, int s)
{
    __shared__ float smem[4608];
    int ntx = s >> 5;
    int tile = blockIdx.x;
    int it = tile / ntx, jt = tile - it * ntx;
    int o = blockIdx.y * 2 * s;
    int col0 = jt * 32, k0 = col0 & ~63;       // B=W11 col j needs k>=j
    gkt(smem, A + (size_t)(o + s) * NDIM + o + k0, NDIM,
        W + (size_t)(o + k0) * NDIM + o, NDIM,
        T + (size_t)(o + s) * NDIM + o, NDIM,
        it * 32, col0, s - k0, 1.f);
}

__global__ __launch_bounds__(256) void pairB2(float* __restrict__ W,
    const float* __restrict__ T, int s)
{
    __shared__ float smem[4608];
    int ntx = s >> 5;
    int tile = blockIdx.x;
    int it = tile / ntx, jt = tile - it * ntx;
    int o = blockIdx.y * 2 * s;
    int ke = (it * 32 + 32 + 63) & ~63; if (ke > s) ke = s;  // A=W22 row r: k<=r
    gkt(smem, W + (size_t)(o + s) * NDIM + (o + s), NDIM,
        T + (size_t)(o + s) * NDIM + o, NDIM,
        W + (size_t)(o + s) * NDIM + o, NDIM,
        it * 32, jt * 32, ke, DT2F);
}

// ---------------------------------------------------------------------------
// form_prep: merged  Ab = 2W - I  |  Bb = dt*W@Bv (tri-clip)  |  Crows[0]=C.
// grid = 385 blocks x 256.
// ---------------------------------------------------------------------------
__global__ __launch_bounds__(256) void form_prep(const float* __restrict__ W,
    const float* __restrict__ Bv, const float* __restrict__ C,
    float* __restrict__ Ab, float* __restrict__ V, float* __restrict__ Crows,
    float* __restrict__ Bbc)
{
    const int b = blockIdx.x, tid = threadIdx.x;
    if (b < 256) {
        int idx = b * 256 + tid;
        int i = idx >> 7, j0 = (idx & 127) << 2;
        float4 wq = *(const float4*)(W + (size_t)i * NDIM + j0);
        float4 r = make_float4(2.f * wq.x, 2.f * wq.y, 2.f * wq.z, 2.f * wq.w);
        if (i == j0)          r.x -= 1.f;
        else if (i == j0 + 1) r.y -= 1.f;
        else if (i == j0 + 2) r.z -= 1.f;
        else if (i == j0 + 3) r.w -= 1.f;
        *(float4*)(Ab + (size_t)i * NDIM + j0) = r;
    } else if (b < 384) {
        const int wv = tid >> 6, lane = tid & 63;
        int i = (b - 256) * 4 + wv;
        float s = 0.f;
        int rmax = i >> 6;                          // W row i: support k<=i
        for (int c = 0; c <= rmax; ++c) {
            int k = (c << 6) + lane;
            if (k <= i) s += W[(size_t)i * NDIM + k] * Bv[k];
        }
#pragma unroll
        for (int off = 32; off; off >>= 1) s += __shfl_xor(s, off, 64);
        if (lane == 0) {
            float bb = DTF * s;
            V[(size_t)i * TCH] = bb;
            Bbc[i] = bb;
        }
    } else {
        Crows[tid]       = C[tid];
        Crows[tid + 256] = C[tid + 256];
    }
}

// ---------------------------------------------------------------------------
// round_kernel: one doubling round, grid (16,16,3). g and all its powers are
// lower-triangular (uppers pre-zeroed once, never written).
//  z=2: gnew = g@g — 136 lower tiles, K clipped to the band.
//  z=0: V[:, m:m+32*nmx) = g @ V[:, :..)  — K clipped by g row support.
//  z=1: Crows[m:..,:] = Crows @ g         — K clipped by g col support.
// For m<32 the 32-wide slab writes garbage into cols/rows [2m, m+32), which
// the next round overwrites before any consumer reads them.
// ---------------------------------------------------------------------------
__global__ __launch_bounds__(256) void round_kernel(const float* __restrict__ g,
    float* __restrict__ gnew, float* __restrict__ V, float* __restrict__ Crows,
    int m, int lognx)
{
    __shared__ float smem[4608];
    const int z = blockIdx.z;
    const int tile_id = blockIdx.y * 16 + blockIdx.x;
    if (z == 2) {
        if (tile_id >= 136) return;
        int it, jt;
        tri_decode(tile_id, it, jt);
        int k0 = (jt * 32) & ~63;
        int ke = (it * 32 + 32 + 63) & ~63; if (ke > NDIM) ke = NDIM;
        gkt(smem, g + k0, NDIM, g + (size_t)k0 * NDIM, NDIM,
            gnew, NDIM, it * 32, jt * 32, ke - k0, 1.f);
    } else if (z == 0) {
        if (m >= TCH) return;
        int nmx = (m >= 32) ? (m >> 5) : 1;
        if (tile_id >= (nmx << 4)) return;
        int it = tile_id >> lognx, jt = tile_id & (nmx - 1);
        int ke = (it * 32 + 32 + 63) & ~63; if (ke > NDIM) ke = NDIM;
        gkt(smem, g, NDIM, V, TCH, V + m, TCH, it * 32, jt * 32, ke, 1.f);
    } else {
        if (m >= TCH) return;
        int nty = (m >= 32) ? (m >> 5) : 1;
        if (tile_id >= (nty << 4)) return;
        int it = tile_id >> 4, jt = tile_id & 15;
        int col0 = jt * 32, k0 = col0 & ~63;
        gkt(smem, Crows + k0, NDIM, g + (size_t)k0 * NDIM, NDIM,
            Crows + (size_t)m * NDIM, NDIM, it * 32, col0, NDIM - k0, 1.f);
    }
}

// ---------------------------------------------------------------------------
// cb_kernel: merged  CrowsS = Crows@Ab (tri)  |  kv  |  build_u.
// grid = 2816 blocks x 256. (512 gemm tasks | 256 kv blocks | 2048 U blocks)
// ---------------------------------------------------------------------------
__global__ __launch_bounds__(256) void cb_kernel(
    const float* __restrict__ Crows, const float* __restrict__ Ab,
    float* __restrict__ CrowsS, const float* __restrict__ Bbc,
    float* __restrict__ kv, const float* __restrict__ V,
    const float* __restrict__ x, const float* __restrict__ GA,
    const float* __restrict__ hs, float* __restrict__ U)
{
    const int t = blockIdx.x;
    const int wv = threadIdx.x >> 6, lane = threadIdx.x & 63;
    if (t < 512) {
        __shared__ float smem[4608];
        int it = t >> 4, jt = t & 15;
        int col0 = jt * 32, k0 = col0 & ~63;   // B=Ab col j: k>=j
        gkt(smem, Crows + k0, NDIM, Ab + (size_t)k0 * NDIM, NDIM,
            CrowsS, NDIM, it * 32, col0, NDIM - k0, 1.f);
    } else if (t < 768) {                      // kv[j] = Crows[j].Bb
        int j = (t - 512) * 4 + wv;
        const float* cr = Crows + (size_t)j * NDIM;
        float dot = 0.f;
#pragma unroll
        for (int rr = 0; rr < 2; ++rr) {
            int o = rr * 256 + lane * 4;
            float4 c4 = *(const float4*)(cr + o);
            float4 b4 = *(const float4*)(Bbc + o);
            dot += c4.x * b4.x + c4.y * b4.y + c4.z * b4.z + c4.w * b4.w;
        }
#pragma unroll
        for (int off = 32; off; off >>= 1) dot += __shfl_xor(dot, off, 64);
        if (lane == 0) kv[j] = dot;
    } else {                                   // build_u
        int wid = (t - 768) * 4 + wv;
        int p = wid & (PCH - 1), i = wid >> 4;
        const float* vr = V + (size_t)i * TCH;
        const float* xc = x + p * TCH;
        float s = 0.f;
#pragma unroll
        for (int rr = 0; rr < 16; ++rr) {
            int t2 = (rr << 6) + lane;
            s += vr[TCH - 1 - t2] * xc[t2];
        }
        if (p == 0) {                          // + GA@h0, GA lower-tri
            const float* gr = GA + (size_t)i * NDIM;
            int rmax = i >> 6;
            for (int rr = 0; rr <= rmax; ++rr) {
                int k = (rr << 6) + lane;
                if (k <= i) s += gr[k] * hs[k];
            }
        }
#pragma unroll
        for (int off = 32; off; off >>= 1) s += __shfl_xor(s, off, 64);
        if (lane == 0) U[(size_t)p * NDIM + i] = s;
    }
}

// ---------------------------------------------------------------------------
// scan_round: Kogge-Stone over 16 chunks; G lower-triangular (tri-clip dot).
// ---------------------------------------------------------------------------
__global__ __launch_bounds__(256) void scan_round(const float* __restrict__ G,
    const float* __restrict__ Zold, float* __restrict__ Znew,
    const float* __restrict__ hs, float* __restrict__ Hmat,
    float* __restrict__ hfin, int o, int last)
{
    int wid = blockIdx.x * 4 + (threadIdx.x >> 6);
    int lane = threadIdx.x & 63;
    int p = wid & (PCH - 1), i = wid >> 4;
    float dot = 0.f;
    if (p >= o) {
        const float* gr = G + (size_t)i * NDIM;
        const float* zc = Zold + (size_t)(p - o) * NDIM;
        int rmax = i >> 6;
        for (int r = 0; r <= rmax; ++r) {
            int k = (r << 6) + lane;
            if (k <= i) dot += gr[k] * zc[k];
        }
#pragma unroll
        for (int off = 32; off; off >>= 1) dot += __shfl_xor(dot, off, 64);
    }
    if (lane == 0) {
        float z = Zold[(size_t)p * NDIM + i] + dot;
        Znew[(size_t)p * NDIM + i] = z;
        if (last) {
            if (p < PCH - 1) Hmat[(size_t)(p + 1) * NDIM + i] = z;
            else hfin[i] = z;
            if (p == 0) Hmat[i] = hs[i];
        }
    }
}

// ---------------------------------------------------------------------------
// emit: y[p*T+s] = CrowsS[s].Hmat[p] + sum_{t<=s} kv[s-t]*x[p*T+t].
// ---------------------------------------------------------------------------
__global__ __launch_bounds__(256) void emit(const float* __restrict__ CrowsS,
    const float* __restrict__ Hmat, const float* __restrict__ kv,
    const float* __restrict__ x, float* __restrict__ out)
{
    int wid = blockIdx.x * 4 + (threadIdx.x >> 6);   // 0..16383
    int lane = threadIdx.x & 63;
    int p = wid & (PCH - 1), s = wid >> 4;
    const float* cr = CrowsS + (size_t)s * NDIM;
    const float* hp = Hmat + (size_t)p * NDIM;
    float dot = 0.f;
#pragma unroll
    for (int r = 0; r < 2; ++r) {
        int o = r * 256 + lane * 4;
        float4 c = *(const float4*)(cr + o);
        float4 h = *(const float4*)(hp + o);
        dot += c.x * h.x + c.y * h.y + c.z * h.z + c.w * h.w;
    }
    const float* xc = x + p * TCH;
    int rmax = s >> 6;
    for (int r = 0; r <= rmax; ++r) {
        int t = (r << 6) + lane;
        if (t <= s) dot += kv[s - t] * xc[t];
    }
#pragma unroll
    for (int off = 32; off; off >>= 1) dot += __shfl_xor(dot, off, 64);
    if (lane == 0) out[p * TCH + s] = dot;
}

// ---------------------------------------------------------------------------
extern "C" void kernel_launch(void* const* d_in, const int* in_sizes, int n_in,
                              void* d_out, int out_size, void* d_ws, size_t ws_size,
                              hipStream_t stream)
{
    (void)in_sizes; (void)n_in; (void)out_size; (void)ws_size;
    const float* x  = (const float*)d_in[0];
    const float* hs = (const float*)d_in[1];
    const float* A  = (const float*)d_in[2];
    const float* Bv = (const float*)d_in[3];
    const float* C  = (const float*)d_in[4];
    float* out = (float*)d_out;                 // [y (16384) | h_final (512)]

    const int MM = NDIM * NDIM;
    float* ws     = (float*)d_ws;
    float* Ab     = ws;
    float* P0     = Ab + MM;
    float* P1     = P0 + MM;
    float* GA     = P1 + MM;                    // Ab^1024
    float* GB     = GA + MM;                    // Ab^2048
    float* GC     = GB + MM;                    // Ab^4096
    float* GD     = GC + MM;                    // Ab^8192
    float* V      = GD + MM;                    // 512 x 1024
    float* Crows  = V + NDIM * TCH;             // 1024 x 512
    float* CrowsS = Crows + TCH * NDIM;         // 1024 x 512 (first 1MB = W)
    float* kv     = CrowsS + TCH * NDIM;        // 1024
    float* Bbc    = kv + TCH;                   // 512
    float* U      = Bbc + NDIM;                 // 16 x 512
    float* Z0     = U + PCH * NDIM;             // 16 x 512
    float* Z1     = Z0 + PCH * NDIM;            // 16 x 512
    float* Hmat   = Z1 + PCH * NDIM;            // 16 x 512

    float* W = CrowsS;  // W dead after form_prep; CrowsS written by cb_kernel.
    float* T = P0;      // pair temp (strictly-lower tiles); round 0 rewrites
                        // all lower tiles of P0; uppers stay zero from memset.

    // ---- zero W (uppers must be 0 for form_ab) and P0..GD (uppers of all
    // g-powers must stay exactly 0 for the triangular K-clips) ----
    hipMemsetAsync(W, 0, MM * sizeof(float), stream);
    hipMemsetAsync(P0, 0, (size_t)6 * MM * sizeof(float), stream);

    // ---- W = (I - dt/2 A)^-1 via blocked inversion ----
    diag_inv<<<8, 64, 0, stream>>>(A, W);
    for (int s = 64; s <= 256; s <<= 1) {
        int np = NDIM / (2 * s);
        int tiles = (s >> 5) * (s >> 5);
        dim3 grid(tiles, np);
        pairA2<<<grid, 256, 0, stream>>>(A, W, T, s);
        pairB2<<<grid, 256, 0, stream>>>(W, T, s);
    }
    form_prep<<<385, 256, 0, stream>>>(W, Bv, C, Ab, V, Crows, Bbc);

    // ---- Krylov doubling (V,Crows to m=1024) + 3 extra squarings for scan ----
    const float* g = Ab;
    float* gouts[13] = {P0, P1, P0, P1, P0, P1, P0, P1, P0, GA, GB, GC, GD};
    int m = 1;
    for (int r = 0; r < 13; ++r) {
        int lognx = (r >= 5) ? (r - 5) : 0;
        round_kernel<<<dim3(16, 16, 3), 256, 0, stream>>>(g, gouts[r], V, Crows,
                                                          m, lognx);
        g = gouts[r];
        m <<= 1;
    }

    // ---- per-chunk pieces: CrowsS = Crows@Ab | kv | U ----
    cb_kernel<<<2816, 256, 0, stream>>>(Crows, Ab, CrowsS, Bbc, kv, V, x, GA,
                                        hs, U);

    // ---- Kogge-Stone scan over chunks: offsets 1,2,4,8 ----
    scan_round<<<2048, 256, 0, stream>>>(GA, U,  Z0, hs, Hmat, out + LSEQ, 1, 0);
    scan_round<<<2048, 256, 0, stream>>>(GB, Z0, Z1, hs, Hmat, out + LSEQ, 2, 0);
    scan_round<<<2048, 256, 0, stream>>>(GC, Z1, Z0, hs, Hmat, out + LSEQ, 4, 0);
    scan_round<<<2048, 256, 0, stream>>>(GD, Z0, Z1, hs, Hmat, out + LSEQ, 8, 1);

    // ---- fused epilogue ----
    emit<<<4096, 256, 0, stream>>>(CrowsS, Hmat, kv, x, out);
}